// Round 1
// baseline (300.254 us; speedup 1.0000x reference)
//
#include <hip/hip_runtime.h>
#include <math.h>

#define N_RAYS    65536
#define N_SAMPLES 192
#define FAR_DELTA 1e4f
#define EPS_DIST  1e-5f
#define EPS_ALPHA 1e-8f

// One wave (64 lanes) per ray. S=192 = 3 chunks of 64 samples; one sample per
// lane per chunk. rgba[ray] is 192 contiguous float4 -> lane i loads float4
// (c*64+i): perfectly coalesced 16B/lane and one full sample per load.
// Exclusive cumprod of (1-alpha+eps) via 6-step shfl_up product scan per
// chunk, with running transmittance T carried between chunks.
__global__ __launch_bounds__(256) void composite_kernel(
    const float* __restrict__ rgba,
    const float* __restrict__ dist,
    float* __restrict__ out)
{
    const int lane = threadIdx.x & 63;
    const int ray  = blockIdx.x * 4 + (threadIdx.x >> 6);
    if (ray >= N_RAYS) return;

    const float4* __restrict__ rgba4 = (const float4*)rgba + (size_t)ray * N_SAMPLES;
    const float*  __restrict__ d     = dist + (size_t)ray * N_SAMPLES;

    float T = 1.0f;                 // running transmittance carry
    float r_acc = 0.f, g_acc = 0.f, b_acc = 0.f;

    #pragma unroll
    for (int c = 0; c < 3; ++c) {
        const int s = c * 64 + lane;
        float4 v = rgba4[s];
        float d0 = d[s];
        float delta = (s + 1 < N_SAMPLES) ? fabsf(d[s + 1] - d0) : FAR_DELTA;

        float density = v.w;
        density = (d0 < EPS_DIST) ? 0.0f : density;
        density = fmaxf(density, 0.0f);          // relu, DENSITY_FACTOR=1

        float alpha = 1.0f - __expf(-delta * density);
        float p = 1.0f - alpha + EPS_ALPHA;

        // 64-lane inclusive product scan
        float P = p;
        #pragma unroll
        for (int off = 1; off < 64; off <<= 1) {
            float t = __shfl_up(P, off, 64);
            if (lane >= off) P *= t;
        }
        // exclusive scan value for this lane
        float E = __shfl_up(P, 1, 64);
        if (lane == 0) E = 1.0f;

        float w = alpha * (T * E);

        // sigmoid of rgb
        float rr = 1.0f / (1.0f + __expf(-v.x));
        float gg = 1.0f / (1.0f + __expf(-v.y));
        float bb = 1.0f / (1.0f + __expf(-v.z));

        r_acc = fmaf(w, rr, r_acc);
        g_acc = fmaf(w, gg, g_acc);
        b_acc = fmaf(w, bb, b_acc);

        // carry total chunk product into next chunk
        T *= __shfl(P, 63, 64);
    }

    // wave reduction of the 3 accumulators
    #pragma unroll
    for (int off = 32; off > 0; off >>= 1) {
        r_acc += __shfl_down(r_acc, off, 64);
        g_acc += __shfl_down(g_acc, off, 64);
        b_acc += __shfl_down(b_acc, off, 64);
    }

    if (lane == 0) {
        out[(size_t)ray * 3 + 0] = r_acc;
        out[(size_t)ray * 3 + 1] = g_acc;
        out[(size_t)ray * 3 + 2] = b_acc;
    }
}

extern "C" void kernel_launch(void* const* d_in, const int* in_sizes, int n_in,
                              void* d_out, int out_size, void* d_ws, size_t ws_size,
                              hipStream_t stream) {
    const float* rgba = (const float*)d_in[0];   // [N_RAYS, N_SAMPLES, 4] f32
    const float* dist = (const float*)d_in[1];   // [N_RAYS, N_SAMPLES]    f32
    float* out = (float*)d_out;                  // [N_RAYS, 3]            f32

    const int rays_per_block = 4;                // 256 threads = 4 waves
    dim3 grid(N_RAYS / rays_per_block);
    dim3 block(256);
    composite_kernel<<<grid, block, 0, stream>>>(rgba, dist, out);
}

// Round 3
// 289.667 us; speedup vs baseline: 1.0366x; 1.0366x over previous
//
#include <hip/hip_runtime.h>
#include <math.h>

#define N_RAYS    65536
#define N_SAMPLES 192
#define FAR_DELTA 1e4f
#define EPS_DIST  1e-5f
#define EPS_ALPHA 1e-8f

typedef float floatx4 __attribute__((ext_vector_type(4)));

// One wave per ray; lane i owns the 3 CONSECUTIVE samples 3i, 3i+1, 3i+2.
// Per-lane serial prefix product (2 muls) + one 6-step wave scan of the
// per-lane totals gives the exclusive cumprod for all 192 samples with only
// 7 shuffle ops (vs 3 chunk-scans + carries). Sigmoid uses v_rcp_f32 instead
// of IEEE division (3 divides/sample was ~21 VALU ops/sample).
__global__ __launch_bounds__(256) void composite_kernel(
    const float* __restrict__ rgba,
    const float* __restrict__ dist,
    float* __restrict__ out)
{
    const int lane = threadIdx.x & 63;
    const int ray  = blockIdx.x * 4 + (threadIdx.x >> 6);

    const floatx4* __restrict__ rgba4 =
        (const floatx4*)rgba + (size_t)ray * N_SAMPLES + lane * 3;
    const float* __restrict__ d =
        dist + (size_t)ray * N_SAMPLES + lane * 3;

    // read-once streams: nontemporal hint
    floatx4 v0 = __builtin_nontemporal_load(rgba4 + 0);
    floatx4 v1 = __builtin_nontemporal_load(rgba4 + 1);
    floatx4 v2 = __builtin_nontemporal_load(rgba4 + 2);
    float d0 = __builtin_nontemporal_load(d + 0);
    float d1 = __builtin_nontemporal_load(d + 1);
    float d2 = __builtin_nontemporal_load(d + 2);
    // next lane's first distance (lane 63 never uses it -> FAR_DELTA)
    float d3 = __shfl_down(d0, 1, 64);

    float dl0 = fabsf(d1 - d0);
    float dl1 = fabsf(d2 - d1);
    float dl2 = (lane == 63) ? FAR_DELTA : fabsf(d3 - d2);

    float den0 = (d0 < EPS_DIST) ? 0.0f : fmaxf(v0.w, 0.0f);
    float den1 = (d1 < EPS_DIST) ? 0.0f : fmaxf(v1.w, 0.0f);
    float den2 = (d2 < EPS_DIST) ? 0.0f : fmaxf(v2.w, 0.0f);

    float t0 = __expf(-dl0 * den0);
    float t1 = __expf(-dl1 * den1);
    float t2 = __expf(-dl2 * den2);

    float a0 = 1.0f - t0, a1 = 1.0f - t1, a2 = 1.0f - t2;
    float p0 = t0 + EPS_ALPHA, p1 = t1 + EPS_ALPHA, p2 = t2 + EPS_ALPHA;

    // per-lane local exclusive prefixes and total
    float e1 = p0;
    float e2 = p0 * p1;
    float Ltot = e2 * p2;

    // 64-lane inclusive product scan of lane totals
    float P = Ltot;
    #pragma unroll
    for (int off = 1; off < 64; off <<= 1) {
        float t = __shfl_up(P, off, 64);
        if (lane >= off) P *= t;
    }
    float E = __shfl_up(P, 1, 64);     // exclusive
    if (lane == 0) E = 1.0f;

    float w0 = a0 * E;
    float w1 = a1 * E * e1;
    float w2 = a2 * E * e2;

    // sigmoid via fast reciprocal
    float r_acc = w0 * __builtin_amdgcn_rcpf(1.0f + __expf(-v0.x))
                + w1 * __builtin_amdgcn_rcpf(1.0f + __expf(-v1.x))
                + w2 * __builtin_amdgcn_rcpf(1.0f + __expf(-v2.x));
    float g_acc = w0 * __builtin_amdgcn_rcpf(1.0f + __expf(-v0.y))
                + w1 * __builtin_amdgcn_rcpf(1.0f + __expf(-v1.y))
                + w2 * __builtin_amdgcn_rcpf(1.0f + __expf(-v2.y));
    float b_acc = w0 * __builtin_amdgcn_rcpf(1.0f + __expf(-v0.z))
                + w1 * __builtin_amdgcn_rcpf(1.0f + __expf(-v1.z))
                + w2 * __builtin_amdgcn_rcpf(1.0f + __expf(-v2.z));

    // wave reduction (3 independent 6-step chains)
    #pragma unroll
    for (int off = 32; off > 0; off >>= 1) {
        r_acc += __shfl_down(r_acc, off, 64);
        g_acc += __shfl_down(g_acc, off, 64);
        b_acc += __shfl_down(b_acc, off, 64);
    }

    if (lane == 0) {
        out[(size_t)ray * 3 + 0] = r_acc;
        out[(size_t)ray * 3 + 1] = g_acc;
        out[(size_t)ray * 3 + 2] = b_acc;
    }
}

extern "C" void kernel_launch(void* const* d_in, const int* in_sizes, int n_in,
                              void* d_out, int out_size, void* d_ws, size_t ws_size,
                              hipStream_t stream) {
    const float* rgba = (const float*)d_in[0];   // [N_RAYS, N_SAMPLES, 4] f32
    const float* dist = (const float*)d_in[1];   // [N_RAYS, N_SAMPLES]    f32
    float* out = (float*)d_out;                  // [N_RAYS, 3]            f32

    dim3 grid(N_RAYS / 4);   // 4 waves = 4 rays per 256-thread block
    dim3 block(256);
    composite_kernel<<<grid, block, 0, stream>>>(rgba, dist, out);
}

// Round 4
// 278.761 us; speedup vs baseline: 1.0771x; 1.0391x over previous
//
#include <hip/hip_runtime.h>
#include <math.h>

#define N_RAYS    65536
#define N_SAMPLES 192
#define FAR_DELTA 1e4f
#define EPS_DIST  1e-5f
#define EPS_ALPHA 1e-8f

typedef float floatx4 __attribute__((ext_vector_type(4)));

// One wave per ray. Lane i loads sample c*64+i for chunks c=0,1,2:
// every global_load_dwordx4 is a fully-contiguous 1 KB wave access
// (vs 48-B lane stride previously = 3 KB scatter / 24 lines per inst).
// The exclusive cumprod over the chunk-major sample order is computed as
// THREE INDEPENDENT 6-step shuffle scans (ILP-pipelined; no serialized
// chunk carry) + two chunk-total broadcasts applied afterwards.
__global__ __launch_bounds__(256) void composite_kernel(
    const float* __restrict__ rgba,
    const float* __restrict__ dist,
    float* __restrict__ out)
{
    const int lane = threadIdx.x & 63;
    const int ray  = blockIdx.x * 4 + (threadIdx.x >> 6);

    const floatx4* __restrict__ rgba4 =
        (const floatx4*)rgba + (size_t)ray * N_SAMPLES + lane;
    const float* __restrict__ d =
        dist + (size_t)ray * N_SAMPLES + lane;

    // coalesced, read-once (nontemporal) loads
    floatx4 v0 = __builtin_nontemporal_load(rgba4 + 0);
    floatx4 v1 = __builtin_nontemporal_load(rgba4 + 64);
    floatx4 v2 = __builtin_nontemporal_load(rgba4 + 128);
    float d0 = __builtin_nontemporal_load(d + 0);
    float d1 = __builtin_nontemporal_load(d + 64);
    float d2 = __builtin_nontemporal_load(d + 128);

    // next-sample distances: s+1 is lane+1 in same chunk, except lane 63
    // crosses into the next chunk's lane 0 (or FAR for the very last sample)
    float dn0 = __shfl_down(d0, 1, 64);
    float dn1 = __shfl_down(d1, 1, 64);
    float dn2 = __shfl_down(d2, 1, 64);
    float b1  = __shfl(d1, 0, 64);   // chunk1 lane0
    float b2  = __shfl(d2, 0, 64);   // chunk2 lane0
    if (lane == 63) { dn0 = b1; dn1 = b2; }

    float dl0 = fabsf(dn0 - d0);
    float dl1 = fabsf(dn1 - d1);
    float dl2 = (lane == 63) ? FAR_DELTA : fabsf(dn2 - d2);

    float den0 = (d0 < EPS_DIST) ? 0.0f : fmaxf(v0.w, 0.0f);
    float den1 = (d1 < EPS_DIST) ? 0.0f : fmaxf(v1.w, 0.0f);
    float den2 = (d2 < EPS_DIST) ? 0.0f : fmaxf(v2.w, 0.0f);

    float t0 = __expf(-dl0 * den0);
    float t1 = __expf(-dl1 * den1);
    float t2 = __expf(-dl2 * den2);

    float a0 = 1.0f - t0, a1 = 1.0f - t1, a2 = 1.0f - t2;
    float P0 = t0 + EPS_ALPHA, P1 = t1 + EPS_ALPHA, P2 = t2 + EPS_ALPHA;

    // three independent 64-lane inclusive product scans (interleaved -> ILP)
    #pragma unroll
    for (int off = 1; off < 64; off <<= 1) {
        float s0 = __shfl_up(P0, off, 64);
        float s1 = __shfl_up(P1, off, 64);
        float s2 = __shfl_up(P2, off, 64);
        if (lane >= off) { P0 *= s0; P1 *= s1; P2 *= s2; }
    }
    // exclusive versions
    float E0 = __shfl_up(P0, 1, 64);
    float E1 = __shfl_up(P1, 1, 64);
    float E2 = __shfl_up(P2, 1, 64);
    if (lane == 0) { E0 = 1.0f; E1 = 1.0f; E2 = 1.0f; }
    // chunk-total carries (applied after the scans; no serial dependency)
    float T1 = __shfl(P0, 63, 64);
    float T2 = T1 * __shfl(P1, 63, 64);

    float w0 = a0 * E0;
    float w1 = a1 * T1 * E1;
    float w2 = a2 * T2 * E2;

    // sigmoid via fast reciprocal (v_rcp_f32)
    float r_acc = w0 * __builtin_amdgcn_rcpf(1.0f + __expf(-v0.x))
                + w1 * __builtin_amdgcn_rcpf(1.0f + __expf(-v1.x))
                + w2 * __builtin_amdgcn_rcpf(1.0f + __expf(-v2.x));
    float g_acc = w0 * __builtin_amdgcn_rcpf(1.0f + __expf(-v0.y))
                + w1 * __builtin_amdgcn_rcpf(1.0f + __expf(-v1.y))
                + w2 * __builtin_amdgcn_rcpf(1.0f + __expf(-v2.y));
    float b_acc = w0 * __builtin_amdgcn_rcpf(1.0f + __expf(-v0.z))
                + w1 * __builtin_amdgcn_rcpf(1.0f + __expf(-v1.z))
                + w2 * __builtin_amdgcn_rcpf(1.0f + __expf(-v2.z));

    // wave reduction (3 independent 6-step chains)
    #pragma unroll
    for (int off = 32; off > 0; off >>= 1) {
        r_acc += __shfl_down(r_acc, off, 64);
        g_acc += __shfl_down(g_acc, off, 64);
        b_acc += __shfl_down(b_acc, off, 64);
    }

    if (lane == 0) {
        out[(size_t)ray * 3 + 0] = r_acc;
        out[(size_t)ray * 3 + 1] = g_acc;
        out[(size_t)ray * 3 + 2] = b_acc;
    }
}

extern "C" void kernel_launch(void* const* d_in, const int* in_sizes, int n_in,
                              void* d_out, int out_size, void* d_ws, size_t ws_size,
                              hipStream_t stream) {
    const float* rgba = (const float*)d_in[0];   // [N_RAYS, N_SAMPLES, 4] f32
    const float* dist = (const float*)d_in[1];   // [N_RAYS, N_SAMPLES]    f32
    float* out = (float*)d_out;                  // [N_RAYS, 3]            f32

    dim3 grid(N_RAYS / 4);   // 4 waves = 4 rays per 256-thread block
    dim3 block(256);
    composite_kernel<<<grid, block, 0, stream>>>(rgba, dist, out);
}